// Round 10
// baseline (75.585 us; speedup 1.0000x reference)
//
#include <hip/hip_runtime.h>
#include <math.h>

#define NC      128   // data columns
#define NSTATE  256   // n_dist_support
#define NITERS  33
#define NSTEPS  6
#define RPB     4     // rows (= independent waves) per block
#define CL2     (-126.22347f)          // log2(1e-38): reference underflow clamp
#define LN2     (0.6931471805599453f)

#define DPP_WAVE_SHL1 0x130   // lane l <- lane l+1 (bound_ctrl: lane63 -> 0)
#define DPP_WAVE_SHR1 0x138   // lane l <- lane l-1 (bound_ctrl: lane0  -> 0)

__device__ __forceinline__ float dpp_shr1(float x) {   // value from lane-1, 0 at lane 0
    return __int_as_float(__builtin_amdgcn_update_dpp(
        0, __float_as_int(x), DPP_WAVE_SHR1, 0xf, 0xf, true));
}
__device__ __forceinline__ float dpp_shl1(float x) {   // value from lane+1, 0 at lane 63
    return __int_as_float(__builtin_amdgcn_update_dpp(
        0, __float_as_int(x), DPP_WAVE_SHL1, 0xf, 0xf, true));
}

// One WAVE per data row; 4 independent waves per block; no __syncthreads anywhere.
// Diffusion states in registers (state 4*lane+j), neighbor exchange via DPP (VALU).
// __launch_bounds__(256,4): pin >=4 waves/SIMD => regalloc capped at 128 VGPR.
__global__ __launch_bounds__(256, 4)
void tonal_diffusion_kernel(const float* __restrict__ data,
                            const float* __restrict__ logw,
                            float* __restrict__ out, int n_rows)
{
    const int wid  = threadIdx.x >> 6;
    const int lane = threadIdx.x & 63;
    const int row  = blockIdx.x * RPB + wid;
    if (row >= n_rows) return;
    const int urow = __builtin_amdgcn_readfirstlane(row);   // wave-uniform row

    // licdR[p][k] = log2(accRaw[k+p]) : 4 rotated copies -> aligned b128 reads
    __shared__ __align__(16) float licdR_s[RPB][4][NSTATE];
    __shared__ __align__(16) float P_s    [RPB][NSTATE];    // inclusive prefix of acc
    float (* __restrict__ licdR)[NSTATE] = licdR_s[wid];
    float * __restrict__ P               = P_s[wid];

    const float* __restrict__ drow = data + (size_t)urow * NC;  // uniform pointer

    // ---- weights: w = exp(lw); rate = sum w; p = w/rate  (steps {1,-1,-3,3,4,-4})
    float rate, p0, p1, p2, p3, p4, p5;
    {
        const float* lw = logw + urow * NSTEPS;
        p0 = __expf(lw[0]); p1 = __expf(lw[1]); p2 = __expf(lw[2]);
        p3 = __expf(lw[3]); p4 = __expf(lw[4]); p5 = __expf(lw[5]);
        rate = ((p0 + p1) + (p2 + p3)) + (p4 + p5);
        const float inv = 1.0f / rate;
        p0 *= inv; p1 *= inv; p2 *= inv; p3 *= inv; p4 *= inv; p5 *= inv;
    }

    // ---- per-lane data (cols 2*lane, 2*lane+1): plogp with zero-guard
    const float2 dl = *(const float2*)(drow + 2 * lane);
    float plogp;
    {
        float pl = 0.f;
        if (dl.x > 1e-8f) pl += dl.x * __logf(dl.x);   // isclose(data,0) excluded
        if (dl.y > 1e-8f) pl += dl.y * __logf(dl.y);
        #pragma unroll
        for (int off = 1; off < 64; off <<= 1) pl += __shfl_xor(pl, off, 64);
        plogp = pl;
    }

    // ---- Poisson-weighted diffusion, registers only; neighbors via DPP (no DS)
    float r0 = 0.f, r1 = 0.f, r2 = 0.f, r3 = 0.f;
    if (lane == 32) r0 = 1.0f;                 // center state 128 = 4*32+0
    float a0 = 0.f, a1 = 0.f, a2 = 0.f, a3 = 0.f;
    float sp = __expf(-rate);                  // Poisson pmf(0)
    #pragma unroll
    for (int n = 0; n < NITERS; ++n) {
        a0 += sp * r0; a1 += sp * r1; a2 += sp * r2; a3 += sp * r3;
        const float L0 = dpp_shr1(r0), L1 = dpp_shr1(r1),
                    L2 = dpp_shr1(r2), L3 = dpp_shr1(r3);   // lane-1 (0 at edge)
        const float R0 = dpp_shl1(r0), R1 = dpp_shl1(r1),
                    R2 = dpp_shl1(r2), R3 = dpp_shl1(r3);   // lane+1 (0 at edge)
        // new[t] = sum_i p[i]*cur[t-steps[i]] ; t = 4*lane + j
        const float n0 = p0*L3 + p1*r1 + p2*r3 + p3*L1 + p4*L0 + p5*R0;
        const float n1 = p0*r0 + p1*r2 + p2*R0 + p3*L2 + p4*L1 + p5*R1;
        const float n2 = p0*r1 + p1*r3 + p2*R1 + p3*L3 + p4*L2 + p5*R2;
        const float n3 = p0*r2 + p1*R0 + p2*R2 + p3*r0 + p4*L3 + p5*R3;
        r0 = n0; r1 = n1; r2 = n2; r3 = n3;
        sp = sp * rate * (1.0f / (float)(n + 1));     // folds under full unroll
    }

    // ---- licd = log2(raw acc); build 4 rotated copies with aligned b128 stores
    {
        const float l0 = __log2f(a0), l1 = __log2f(a1),
                    l2 = __log2f(a2), l3 = __log2f(a3);
        const float nl0 = dpp_shl1(l0), nl1 = dpp_shl1(l1), nl2 = dpp_shl1(l2);
        // copy p at [4l..4l+3] holds licd[4l+p .. 4l+3+p] (tail entries unused)
        *(float4*)&licdR[0][4 * lane] = make_float4(l0, l1, l2, l3);
        *(float4*)&licdR[1][4 * lane] = make_float4(l1, l2, l3, nl0);
        *(float4*)&licdR[2][4 * lane] = make_float4(l2, l3, nl0, nl1);
        *(float4*)&licdR[3][4 * lane] = make_float4(l3, nl0, nl1, nl2);
    }

    // ---- inclusive prefix sum P of raw acc (in-lane serial + wave scan)
    {
        const float s0 = a0, s1 = s0 + a1, s2 = s1 + a2, s3 = s2 + a3;
        float t = s3;
        #pragma unroll
        for (int off = 1; off < 64; off <<= 1) {
            const float u = __shfl_up(t, off, 64);
            if (lane >= off) t += u;
        }
        const float base = t - s3;
        *(float4*)&P[4 * lane] = make_float4(base + s0, base + s1, base + s2, base + s3);
    }

    // ---- matching: shifts sA=lane, sB=lane+64 share one aligned licd float4 stream.
    // log q = licd[s+c] - log2(Z_s); per-term clamp at log2(1e-38) == reference.
    // d factor: wave-uniform float4 loads (SMEM-eligible s_load_dwordx4).
    const int phi = lane & 3;
    const float* __restrict__ lcp = &licdR[phi][lane - phi];   // 16B-aligned per lane
    const float zA = __log2f(P[lane + 127] - (lane ? P[lane - 1] : 0.f));
    const float zB = __log2f(P[lane + 191] - P[lane + 63]);
    float accA = 0.f, accB = 0.f;
    #pragma unroll 4
    for (int m = 0; m < 16; ++m) {             // sA cols 0..63
        const float4 v = *(const float4*)(lcp + 4 * m);
        const float4 d = *(const float4*)(drow + 4 * m);
        accA += d.x * fmaxf(v.x - zA, CL2);
        accA += d.y * fmaxf(v.y - zA, CL2);
        accA += d.z * fmaxf(v.z - zA, CL2);
        accA += d.w * fmaxf(v.w - zA, CL2);
    }
    #pragma unroll 4
    for (int m = 16; m < 32; ++m) {            // sA cols 64..127 / sB cols 0..63
        const float4 v  = *(const float4*)(lcp + 4 * m);
        const float4 dA = *(const float4*)(drow + 4 * m);
        const float4 dB = *(const float4*)(drow + 4 * m - 64);
        accA += dA.x * fmaxf(v.x - zA, CL2);
        accA += dA.y * fmaxf(v.y - zA, CL2);
        accA += dA.z * fmaxf(v.z - zA, CL2);
        accA += dA.w * fmaxf(v.w - zA, CL2);
        accB += dB.x * fmaxf(v.x - zB, CL2);
        accB += dB.y * fmaxf(v.y - zB, CL2);
        accB += dB.z * fmaxf(v.z - zB, CL2);
        accB += dB.w * fmaxf(v.w - zB, CL2);
    }
    #pragma unroll 4
    for (int m = 32; m < 48; ++m) {            // sB cols 64..127
        const float4 v  = *(const float4*)(lcp + 4 * m);
        const float4 dB = *(const float4*)(drow + 4 * m - 64);
        accB += dB.x * fmaxf(v.x - zB, CL2);
        accB += dB.y * fmaxf(v.y - zB, CL2);
        accB += dB.z * fmaxf(v.z - zB, CL2);
        accB += dB.w * fmaxf(v.w - zB, CL2);
    }
    float best = fminf(plogp - LN2 * accA, plogp - LN2 * accB);

    // ---- shift 128: 2 cols/lane (raw local data) + wave reduce
    {
        const float z = __log2f(P[255] - P[127]);
        const float2 lv = *(const float2*)(&licdR[0][128 + 2 * lane]);  // 8B aligned
        float part = dl.x * fmaxf(lv.x - z, CL2) + dl.y * fmaxf(lv.y - z, CL2);
        #pragma unroll
        for (int off = 1; off < 64; off <<= 1) part += __shfl_xor(part, off, 64);
        best = fminf(best, plogp - LN2 * part);
    }

    // ---- wave min, lane 0 stores
    #pragma unroll
    for (int off = 1; off < 64; off <<= 1) best = fminf(best, __shfl_xor(best, off, 64));
    if (lane == 0) out[row] = best;
}

extern "C" void kernel_launch(void* const* d_in, const int* in_sizes, int n_in,
                              void* d_out, int out_size, void* d_ws, size_t ws_size,
                              hipStream_t stream)
{
    const float* data = (const float*)d_in[0];   // [n, 128] f32
    const float* logw = (const float*)d_in[1];   // [n, 6]   f32
    float* out = (float*)d_out;                  // [n]      f32
    const int n_rows = in_sizes[0] / NC;
    const int blocks = (n_rows + RPB - 1) / RPB;
    tonal_diffusion_kernel<<<blocks, 256, 0, stream>>>(data, logw, out, n_rows);
}

// Round 11
// 73.536 us; speedup vs baseline: 1.0279x; 1.0279x over previous
//
#include <hip/hip_runtime.h>
#include <math.h>

#define NC      128   // data columns
#define NSTATE  256   // n_dist_support
#define NITERS  33
#define NSTEPS  6
#define RPB     4     // rows (= independent waves) per block
#define LN2     (0.6931471805599453f)

#define DPP_WAVE_SHL1 0x130   // lane l <- lane l+1 (bound_ctrl: lane63 -> 0)
#define DPP_WAVE_SHR1 0x138   // lane l <- lane l-1 (bound_ctrl: lane0  -> 0)

__device__ __forceinline__ float dpp_shr1(float x) {   // value from lane-1, 0 at lane 0
    return __int_as_float(__builtin_amdgcn_update_dpp(
        0, __float_as_int(x), DPP_WAVE_SHR1, 0xf, 0xf, true));
}
__device__ __forceinline__ float dpp_shl1(float x) {   // value from lane+1, 0 at lane 63
    return __int_as_float(__builtin_amdgcn_update_dpp(
        0, __float_as_int(x), DPP_WAVE_SHL1, 0xf, 0xf, true));
}

// One WAVE per data row; 4 independent waves per block; no __syncthreads anywhere.
// Diffusion states in registers (state 4*lane+j), neighbor exchange via DPP (VALU).
// Matching: loss(s) = plogp + ln2*(log2(Z_s) - dot(d, licd[s:s+128])), using
// sum(d)=1 (rows normalized). Per-term underflow clamp removed: it is the
// identity at the winning shift (q >= ~1e-13 there); clamped/underflowed edge
// shifts only produce LARGER losses (+inf at worst) and NaNs are dropped by
// v_min_f32's non-NaN-operand semantics, so the min is unchanged.
__global__ __launch_bounds__(256, 4)
void tonal_diffusion_kernel(const float* __restrict__ data,
                            const float* __restrict__ logw,
                            float* __restrict__ out, int n_rows)
{
    const int wid  = threadIdx.x >> 6;
    const int lane = threadIdx.x & 63;
    const int row  = blockIdx.x * RPB + wid;
    if (row >= n_rows) return;
    const int urow = __builtin_amdgcn_readfirstlane(row);   // wave-uniform row

    // licdR[p][k] = log2(accRaw[k+p]) : 4 rotated copies -> aligned b128 reads
    __shared__ __align__(16) float licdR_s[RPB][4][NSTATE];
    __shared__ __align__(16) float P_s    [RPB][NSTATE];    // inclusive prefix of acc
    __shared__ __align__(16) float dsh_s  [RPB][NC];        // raw data row
    float (* __restrict__ licdR)[NSTATE] = licdR_s[wid];
    float * __restrict__ P               = P_s[wid];
    float * __restrict__ dsh             = dsh_s[wid];

    const float* __restrict__ drow = data + (size_t)urow * NC;  // uniform pointer

    // ---- weights: w = exp(lw); rate = sum w; p = w/rate  (steps {1,-1,-3,3,4,-4})
    float rate, p0, p1, p2, p3, p4, p5;
    {
        const float* lw = logw + urow * NSTEPS;
        p0 = __expf(lw[0]); p1 = __expf(lw[1]); p2 = __expf(lw[2]);
        p3 = __expf(lw[3]); p4 = __expf(lw[4]); p5 = __expf(lw[5]);
        rate = ((p0 + p1) + (p2 + p3)) + (p4 + p5);
        const float inv = 1.0f / rate;
        p0 *= inv; p1 *= inv; p2 *= inv; p3 *= inv; p4 *= inv; p5 *= inv;
    }

    // ---- per-lane data (cols 2*lane, 2*lane+1): stash raw row in LDS; plogp
    const float2 dl = *(const float2*)(drow + 2 * lane);
    *(float2*)(dsh + 2 * lane) = dl;
    float plogp;
    {
        float pl = 0.f;
        if (dl.x > 1e-8f) pl += dl.x * __logf(dl.x);   // isclose(data,0) excluded
        if (dl.y > 1e-8f) pl += dl.y * __logf(dl.y);
        #pragma unroll
        for (int off = 1; off < 64; off <<= 1) pl += __shfl_xor(pl, off, 64);
        plogp = pl;
    }

    // ---- Poisson-weighted diffusion, registers only; neighbors via DPP (no DS)
    float r0 = 0.f, r1 = 0.f, r2 = 0.f, r3 = 0.f;
    if (lane == 32) r0 = 1.0f;                 // center state 128 = 4*32+0
    float a0 = 0.f, a1 = 0.f, a2 = 0.f, a3 = 0.f;
    float sp = __expf(-rate);                  // Poisson pmf(0)
    #pragma unroll
    for (int n = 0; n < NITERS; ++n) {
        a0 += sp * r0; a1 += sp * r1; a2 += sp * r2; a3 += sp * r3;
        const float L0 = dpp_shr1(r0), L1 = dpp_shr1(r1),
                    L2 = dpp_shr1(r2), L3 = dpp_shr1(r3);   // lane-1 (0 at edge)
        const float R0 = dpp_shl1(r0), R1 = dpp_shl1(r1),
                    R2 = dpp_shl1(r2), R3 = dpp_shl1(r3);   // lane+1 (0 at edge)
        // new[t] = sum_i p[i]*cur[t-steps[i]] ; t = 4*lane + j
        const float n0 = p0*L3 + p1*r1 + p2*r3 + p3*L1 + p4*L0 + p5*R0;
        const float n1 = p0*r0 + p1*r2 + p2*R0 + p3*L2 + p4*L1 + p5*R1;
        const float n2 = p0*r1 + p1*r3 + p2*R1 + p3*L3 + p4*L2 + p5*R2;
        const float n3 = p0*r2 + p1*R0 + p2*R2 + p3*r0 + p4*L3 + p5*R3;
        r0 = n0; r1 = n1; r2 = n2; r3 = n3;
        sp = sp * rate * (1.0f / (float)(n + 1));     // folds under full unroll
    }

    // ---- licd = log2(raw acc); build 4 rotated copies with aligned b128 stores
    {
        const float l0 = __log2f(a0), l1 = __log2f(a1),
                    l2 = __log2f(a2), l3 = __log2f(a3);
        const float nl0 = dpp_shl1(l0), nl1 = dpp_shl1(l1), nl2 = dpp_shl1(l2);
        // copy p at [4l..4l+3] holds licd[4l+p .. 4l+3+p] (tail entries unused)
        *(float4*)&licdR[0][4 * lane] = make_float4(l0, l1, l2, l3);
        *(float4*)&licdR[1][4 * lane] = make_float4(l1, l2, l3, nl0);
        *(float4*)&licdR[2][4 * lane] = make_float4(l2, l3, nl0, nl1);
        *(float4*)&licdR[3][4 * lane] = make_float4(l3, nl0, nl1, nl2);
    }

    // ---- inclusive prefix sum P of raw acc (in-lane serial + wave scan)
    {
        const float s0 = a0, s1 = s0 + a1, s2 = s1 + a2, s3 = s2 + a3;
        float t = s3;
        #pragma unroll
        for (int off = 1; off < 64; off <<= 1) {
            const float u = __shfl_up(t, off, 64);
            if (lane >= off) t += u;
        }
        const float base = t - s3;
        *(float4*)&P[4 * lane] = make_float4(base + s0, base + s1, base + s2, base + s3);
    }

    // ---- matching: shifts sA=lane, sB=lane+64 share one aligned licd float4
    // stream; d comes from broadcast (same-address, conflict-free) LDS reads.
    // best2 = min_s (log2(Z_s) - dot2(d, licd window)); loss = plogp + ln2*best2.
    const int phi = lane & 3;
    const float* __restrict__ lcp = &licdR[phi][lane - phi];   // 16B-aligned per lane
    const float zA2 = __log2f(P[lane + 127] - (lane ? P[lane - 1] : 0.f));
    const float zB2 = __log2f(P[lane + 191] - P[lane + 63]);
    float dotA = 0.f, dotB = 0.f;
    #pragma unroll 4
    for (int m = 0; m < 16; ++m) {             // sA cols 0..63
        const float4 v = *(const float4*)(lcp + 4 * m);
        const float4 d = *(const float4*)(dsh + 4 * m);
        dotA += d.x * v.x; dotA += d.y * v.y;
        dotA += d.z * v.z; dotA += d.w * v.w;
    }
    #pragma unroll 4
    for (int m = 16; m < 32; ++m) {            // sA cols 64..127 / sB cols 0..63
        const float4 v  = *(const float4*)(lcp + 4 * m);
        const float4 dA = *(const float4*)(dsh + 4 * m);
        const float4 dB = *(const float4*)(dsh + 4 * m - 64);
        dotA += dA.x * v.x; dotA += dA.y * v.y;
        dotA += dA.z * v.z; dotA += dA.w * v.w;
        dotB += dB.x * v.x; dotB += dB.y * v.y;
        dotB += dB.z * v.z; dotB += dB.w * v.w;
    }
    #pragma unroll 4
    for (int m = 32; m < 48; ++m) {            // sB cols 64..127
        const float4 v  = *(const float4*)(lcp + 4 * m);
        const float4 dB = *(const float4*)(dsh + 4 * m - 64);
        dotB += dB.x * v.x; dotB += dB.y * v.y;
        dotB += dB.z * v.z; dotB += dB.w * v.w;
    }
    float best2 = fminf(zA2 - dotA, zB2 - dotB);

    // ---- shift 128: 2 cols/lane (local data regs) + wave reduce
    {
        const float z2 = __log2f(P[255] - P[127]);
        const float2 lv = *(const float2*)(&licdR[0][128 + 2 * lane]);  // 8B aligned
        float part = dl.x * lv.x + dl.y * lv.y;
        #pragma unroll
        for (int off = 1; off < 64; off <<= 1) part += __shfl_xor(part, off, 64);
        best2 = fminf(best2, z2 - part);
    }

    // ---- wave min, lane 0 stores
    #pragma unroll
    for (int off = 1; off < 64; off <<= 1) best2 = fminf(best2, __shfl_xor(best2, off, 64));
    if (lane == 0) out[row] = plogp + LN2 * best2;
}

extern "C" void kernel_launch(void* const* d_in, const int* in_sizes, int n_in,
                              void* d_out, int out_size, void* d_ws, size_t ws_size,
                              hipStream_t stream)
{
    const float* data = (const float*)d_in[0];   // [n, 128] f32
    const float* logw = (const float*)d_in[1];   // [n, 6]   f32
    float* out = (float*)d_out;                  // [n]      f32
    const int n_rows = in_sizes[0] / NC;
    const int blocks = (n_rows + RPB - 1) / RPB;
    tonal_diffusion_kernel<<<blocks, 256, 0, stream>>>(data, logw, out, n_rows);
}

// Round 12
// 72.232 us; speedup vs baseline: 1.0464x; 1.0180x over previous
//
#include <hip/hip_runtime.h>
#include <math.h>

#define NC      128   // data columns
#define NSTATE  256   // n_dist_support
#define NITERS  33
#define NSTEPS  6
#define RPB     4     // rows (= independent waves) per block
#define LN2     (0.6931471805599453f)

#define DPP_WAVE_SHL1 0x130   // lane l <- lane l+1 (bound_ctrl: lane63 -> 0)
#define DPP_WAVE_SHR1 0x138   // lane l <- lane l-1 (bound_ctrl: lane0  -> 0)

__device__ __forceinline__ float dpp_shr1(float x) {   // value from lane-1, 0 at lane 0
    return __int_as_float(__builtin_amdgcn_update_dpp(
        0, __float_as_int(x), DPP_WAVE_SHR1, 0xf, 0xf, true));
}
__device__ __forceinline__ float dpp_shl1(float x) {   // value from lane+1, 0 at lane 63
    return __int_as_float(__builtin_amdgcn_update_dpp(
        0, __float_as_int(x), DPP_WAVE_SHL1, 0xf, 0xf, true));
}

// One WAVE per data row; 4 independent waves per block; no __syncthreads anywhere.
// Diffusion states in registers (state 4*lane+j), neighbor exchange via DPP (VALU).
// Matching: loss(s) = plogp + ln2*(log2(Z_s) - dot(d, licd[s:s+128]))  (sum d = 1).
// DS-diet: d-vector read from global via wave-uniform address (s_load/SMEM-eligible,
// off the DS pipe); licd stream deduped via the identity lane+4(j+16)=lane+64+4j.
__global__ __launch_bounds__(256, 4)
void tonal_diffusion_kernel(const float* __restrict__ data,
                            const float* __restrict__ logw,
                            float* __restrict__ out, int n_rows)
{
    const int wid  = threadIdx.x >> 6;
    const int lane = threadIdx.x & 63;
    int row = blockIdx.x * RPB + wid;
    row = row < n_rows ? row : n_rows - 1;   // uniform clamp, no divergent return
    const int urow = __builtin_amdgcn_readfirstlane(row);   // wave-uniform row

    // licdR[p][k] = log2(accRaw[k+p]) : 4 rotated copies -> aligned b128 reads
    __shared__ __align__(16) float licdR_s[RPB][4][NSTATE];
    __shared__ __align__(16) float P_s    [RPB][NSTATE];    // inclusive prefix of acc
    float (* __restrict__ licdR)[NSTATE] = licdR_s[wid];
    float * __restrict__ P               = P_s[wid];

    const float* __restrict__ drow = data + (size_t)urow * NC;  // uniform pointer

    // ---- weights: w = exp(lw); rate = sum w; p = w/rate  (steps {1,-1,-3,3,4,-4})
    float rate, p0, p1, p2, p3, p4, p5;
    {
        const float* lw = logw + urow * NSTEPS;
        p0 = __expf(lw[0]); p1 = __expf(lw[1]); p2 = __expf(lw[2]);
        p3 = __expf(lw[3]); p4 = __expf(lw[4]); p5 = __expf(lw[5]);
        rate = ((p0 + p1) + (p2 + p3)) + (p4 + p5);
        const float inv = 1.0f / rate;
        p0 *= inv; p1 *= inv; p2 *= inv; p3 *= inv; p4 *= inv; p5 *= inv;
    }

    // ---- per-lane data (cols 2*lane, 2*lane+1): plogp with zero-guard
    const float2 dl = *(const float2*)(drow + 2 * lane);
    float plogp;
    {
        float pl = 0.f;
        if (dl.x > 1e-8f) pl += dl.x * __logf(dl.x);   // isclose(data,0) excluded
        if (dl.y > 1e-8f) pl += dl.y * __logf(dl.y);
        #pragma unroll
        for (int off = 1; off < 64; off <<= 1) pl += __shfl_xor(pl, off, 64);
        plogp = pl;
    }

    // ---- Poisson-weighted diffusion, registers only; neighbors via DPP (no DS)
    float r0 = 0.f, r1 = 0.f, r2 = 0.f, r3 = 0.f;
    if (lane == 32) r0 = 1.0f;                 // center state 128 = 4*32+0
    float a0 = 0.f, a1 = 0.f, a2 = 0.f, a3 = 0.f;
    float sp = __expf(-rate);                  // Poisson pmf(0)
    #pragma unroll
    for (int n = 0; n < NITERS; ++n) {
        a0 += sp * r0; a1 += sp * r1; a2 += sp * r2; a3 += sp * r3;
        const float L0 = dpp_shr1(r0), L1 = dpp_shr1(r1),
                    L2 = dpp_shr1(r2), L3 = dpp_shr1(r3);   // lane-1 (0 at edge)
        const float R0 = dpp_shl1(r0), R1 = dpp_shl1(r1),
                    R2 = dpp_shl1(r2), R3 = dpp_shl1(r3);   // lane+1 (0 at edge)
        // new[t] = sum_i p[i]*cur[t-steps[i]] ; t = 4*lane + j
        const float n0 = p0*L3 + p1*r1 + p2*r3 + p3*L1 + p4*L0 + p5*R0;
        const float n1 = p0*r0 + p1*r2 + p2*R0 + p3*L2 + p4*L1 + p5*R1;
        const float n2 = p0*r1 + p1*r3 + p2*R1 + p3*L3 + p4*L2 + p5*R2;
        const float n3 = p0*r2 + p1*R0 + p2*R2 + p3*r0 + p4*L3 + p5*R3;
        r0 = n0; r1 = n1; r2 = n2; r3 = n3;
        sp = sp * rate * (1.0f / (float)(n + 1));     // folds under full unroll
    }

    // ---- licd = log2(raw acc); build 4 rotated copies with aligned b128 stores
    {
        const float l0 = __log2f(a0), l1 = __log2f(a1),
                    l2 = __log2f(a2), l3 = __log2f(a3);
        const float nl0 = dpp_shl1(l0), nl1 = dpp_shl1(l1), nl2 = dpp_shl1(l2);
        // copy p at [4l..4l+3] holds licd[4l+p .. 4l+3+p] (tail entries unused)
        *(float4*)&licdR[0][4 * lane] = make_float4(l0, l1, l2, l3);
        *(float4*)&licdR[1][4 * lane] = make_float4(l1, l2, l3, nl0);
        *(float4*)&licdR[2][4 * lane] = make_float4(l2, l3, nl0, nl1);
        *(float4*)&licdR[3][4 * lane] = make_float4(l3, nl0, nl1, nl2);
    }

    // ---- inclusive prefix sum P of raw acc (in-lane serial + wave scan)
    {
        const float s0 = a0, s1 = s0 + a1, s2 = s1 + a2, s3 = s2 + a3;
        float t = s3;
        #pragma unroll
        for (int off = 1; off < 64; off <<= 1) {
            const float u = __shfl_up(t, off, 64);
            if (lane >= off) t += u;
        }
        const float base = t - s3;
        *(float4*)&P[4 * lane] = make_float4(base + s0, base + s1, base + s2, base + s3);
    }

    // ---- matching: shifts sA=lane, sB=lane+64. Deduped licd stream:
    // L2 = licd[lane+64+4j] serves BOTH dotA cols 64.. (j+16) and dotB cols 0..63.
    // d blocks from global (uniform addr -> scalar pipe), not LDS.
    const int phi = lane & 3;
    const float* __restrict__ lcp = &licdR[phi][lane - phi];   // 16B-aligned per lane
    const float zA2 = __log2f(P[lane + 127] - (lane ? P[lane - 1] : 0.f));
    const float zB2 = __log2f(P[lane + 191] - P[lane + 63]);
    float dotA = 0.f, dotB = 0.f;
    #pragma unroll 4
    for (int j = 0; j < 16; ++j) {
        const float4 L1v = *(const float4*)(lcp + 4 * j);          // licd[lane+4j]
        const float4 L2v = *(const float4*)(lcp + 4 * j + 64);     // licd[lane+64+4j]
        const float4 L3v = *(const float4*)(lcp + 4 * j + 128);    // licd[lane+128+4j]
        const float4 dLo = *(const float4*)(drow + 4 * j);         // d[4j..]   uniform
        const float4 dHi = *(const float4*)(drow + 4 * j + 64);    // d[64+4j..] uniform
        dotA += dLo.x * L1v.x; dotA += dLo.y * L1v.y;
        dotA += dLo.z * L1v.z; dotA += dLo.w * L1v.w;
        dotA += dHi.x * L2v.x; dotA += dHi.y * L2v.y;
        dotA += dHi.z * L2v.z; dotA += dHi.w * L2v.w;
        dotB += dLo.x * L2v.x; dotB += dLo.y * L2v.y;
        dotB += dLo.z * L2v.z; dotB += dLo.w * L2v.w;
        dotB += dHi.x * L3v.x; dotB += dHi.y * L3v.y;
        dotB += dHi.z * L3v.z; dotB += dHi.w * L3v.w;
    }
    float best2 = fminf(zA2 - dotA, zB2 - dotB);

    // ---- shift 128: 2 cols/lane (local data regs) + wave reduce
    {
        const float z2 = __log2f(P[255] - P[127]);
        const float2 lv = *(const float2*)(&licdR[0][128 + 2 * lane]);  // 8B aligned
        float part = dl.x * lv.x + dl.y * lv.y;
        #pragma unroll
        for (int off = 1; off < 64; off <<= 1) part += __shfl_xor(part, off, 64);
        best2 = fminf(best2, z2 - part);
    }

    // ---- wave min, lane 0 stores (tail clamp waves write identical value)
    #pragma unroll
    for (int off = 1; off < 64; off <<= 1) best2 = fminf(best2, __shfl_xor(best2, off, 64));
    if (lane == 0) out[row] = plogp + LN2 * best2;
}

extern "C" void kernel_launch(void* const* d_in, const int* in_sizes, int n_in,
                              void* d_out, int out_size, void* d_ws, size_t ws_size,
                              hipStream_t stream)
{
    const float* data = (const float*)d_in[0];   // [n, 128] f32
    const float* logw = (const float*)d_in[1];   // [n, 6]   f32
    float* out = (float*)d_out;                  // [n]      f32
    const int n_rows = in_sizes[0] / NC;
    const int blocks = (n_rows + RPB - 1) / RPB;
    tonal_diffusion_kernel<<<blocks, 256, 0, stream>>>(data, logw, out, n_rows);
}